// Round 2
// baseline (1291.719 us; speedup 1.0000x reference)
//
#include <hip/hip_runtime.h>
#include <hip/hip_fp16.h>

#define ITERS 100
#define AGENT __HIP_MEMORY_SCOPE_AGENT
#define WG    __HIP_MEMORY_SCOPE_WORKGROUP

// 8-byte message: fp32 value + iteration tag, moved as ONE relaxed agent-scope
// atomic. Tag==it+1 validates the value (poison 0xAAAAAAAA never matches).
// Poll-is-read: observing the tag IS both detection and data delivery.
//
// ROLE SPLIT (this round): waves 0-1 (pair0) = u-producer + v-consumer;
// waves 2-3 (pair1) = u-consumer + v-producer. Each pair polls the fabric
// WHILE the other pair runs its matvec, so detect cost ~= store visibility.
// No __syncthreads inside the 200-phase loop; intra-block handoffs go through
// block-private L1-resident scratch with workgroup-scope acquire/release.
union PK { unsigned long long u; struct { float v; unsigned tag; } s; };

// ws layout (8-byte units):
//   rmsg[2][16][16][136] : u-phase, [buf][bi][src_bj][row 0..127, 128 = src stripe vsum]
//   cmsg[2][16][16][136] : v-phase, [buf][bj][src_bi][col 0..127, 128 = src stripe usum]
//   then per-block fp32 scratch (block-private, L1-resident):
//     [0..127] ubuf, [128..255] vbuf, [256..259] wave partial sums,
//     [260..263] rendezvous flags, [264..267] uN/vN mailboxes (PK)
#define SLOT 136
#define MSG_ONE (2 * 16 * 16 * SLOT)
#define SCRF 320

__device__ __forceinline__ float wave_sum(float p) {
    p += __shfl_xor(p, 1, 64);
    p += __shfl_xor(p, 2, 64);
    p += __shfl_xor(p, 4, 64);
    p += __shfl_xor(p, 8, 64);
    p += __shfl_xor(p, 16, 64);
    p += __shfl_xor(p, 32, 64);
    return p;
}

__global__ void __launch_bounds__(256, 1)
sinkhorn_fused(const float* __restrict__ Q, const float* __restrict__ R,
               const float* __restrict__ zp, float* __restrict__ out,
               unsigned long long* __restrict__ ws)
{
    // 64 KiB LDS. GEMM staging first, then the two fp16 tile copies.
    __shared__ __align__(16) char smem[65536];
    float* As = (float*)smem;               // [2][32][128] k-major A slabs
    float* Bs = (float*)(smem + 32768);     // [2][32][128] k-major B slabs
    char*  TrmB = smem;                     // [128 rows][16 chunks of 16B], chunk-swizzled
    char*  TcmB = smem + 32768;             // [128 cols][16 chunks of 16B], chunk-swizzled

    const int t  = threadIdx.x;
    const int b  = blockIdx.x;
    const int bi = b >> 4, bj = b & 15;
    const int tx = t & 15, ty = t >> 4;
    const int l  = t & 63, w  = t >> 6;
    const int gi0 = bi * 128, gj0 = bj * 128;

    // ---------------- phase 1: 128x128 score tile, fp32 GEMM K=512 ----------------
    float acc[8][8];
#pragma unroll
    for (int r = 0; r < 8; r++)
#pragma unroll
        for (int c = 0; c < 8; c++) acc[r][c] = 0.f;

    const int lr = t & 31, lc4 = t >> 5;
    const float* Qb = Q + (size_t)gi0 * 512;
    const float* Rb = R + (size_t)gj0 * 512;

    float4 qa[4], ra[4];
#pragma unroll
    for (int i = 0; i < 4; i++) {
        qa[i] = *(const float4*)(Qb + (size_t)(lr + 32 * i) * 512 + 4 * lc4);
        ra[i] = *(const float4*)(Rb + (size_t)(lr + 32 * i) * 512 + 4 * lc4);
    }
#pragma unroll
    for (int i = 0; i < 4; i++) {
        int row = lr + 32 * i;
        As[(4*lc4+0)*128 + row] = qa[i].x;  As[(4*lc4+1)*128 + row] = qa[i].y;
        As[(4*lc4+2)*128 + row] = qa[i].z;  As[(4*lc4+3)*128 + row] = qa[i].w;
        Bs[(4*lc4+0)*128 + row] = ra[i].x;  Bs[(4*lc4+1)*128 + row] = ra[i].y;
        Bs[(4*lc4+2)*128 + row] = ra[i].z;  Bs[(4*lc4+3)*128 + row] = ra[i].w;
    }
    __syncthreads();

    for (int ks = 0; ks < 16; ks++) {
        if (ks < 15) {
            int k0 = (ks + 1) * 32;
#pragma unroll
            for (int i = 0; i < 4; i++) {
                qa[i] = *(const float4*)(Qb + (size_t)(lr+32*i)*512 + k0 + 4*lc4);
                ra[i] = *(const float4*)(Rb + (size_t)(lr+32*i)*512 + k0 + 4*lc4);
            }
        }
        const float* A = As + (ks & 1) * (32 * 128);
        const float* B = Bs + (ks & 1) * (32 * 128);
#pragma unroll 4
        for (int k = 0; k < 32; k++) {
            float4 a0 = *(const float4*)(A + k*128 + 8*ty);
            float4 a1 = *(const float4*)(A + k*128 + 8*ty + 4);
            float4 b0 = *(const float4*)(B + k*128 + 8*tx);
            float4 b1 = *(const float4*)(B + k*128 + 8*tx + 4);
            float av[8] = {a0.x,a0.y,a0.z,a0.w,a1.x,a1.y,a1.z,a1.w};
            float bv[8] = {b0.x,b0.y,b0.z,b0.w,b1.x,b1.y,b1.z,b1.w};
#pragma unroll
            for (int r = 0; r < 8; r++)
#pragma unroll
                for (int c = 0; c < 8; c++)
                    acc[r][c] = fmaf(av[r], bv[c], acc[r][c]);
        }
        if (ks < 15) {
            __syncthreads();
            float* An = As + ((ks+1) & 1) * (32 * 128);
            float* Bn = Bs + ((ks+1) & 1) * (32 * 128);
#pragma unroll
            for (int i = 0; i < 4; i++) {
                int row = lr + 32 * i;
                An[(4*lc4+0)*128 + row] = qa[i].x;  An[(4*lc4+1)*128 + row] = qa[i].y;
                An[(4*lc4+2)*128 + row] = qa[i].z;  An[(4*lc4+3)*128 + row] = qa[i].w;
                Bn[(4*lc4+0)*128 + row] = ra[i].x;  Bn[(4*lc4+1)*128 + row] = ra[i].y;
                Bn[(4*lc4+2)*128 + row] = ra[i].z;  Bn[(4*lc4+3)*128 + row] = ra[i].w;
            }
            __syncthreads();
        }
    }
    __syncthreads();                        // As/Bs dead; LDS becomes Trm/Tcm

    // ---------------- phase 2: K0 = exp(score*10) -> swizzled fp16 tiles ----------------
    const float E = expf(zp[0] * 10.0f);
#pragma unroll
    for (int r = 0; r < 8; r++)
#pragma unroll
        for (int c = 0; c < 8; c++) acc[r][c] = expf(acc[r][c] * 10.0f);

#pragma unroll
    for (int r = 0; r < 8; r++) {           // row-major tile: one 16B chunk per row
        int rr = 8 * ty + r;
        unsigned short h[8];
#pragma unroll
        for (int c = 0; c < 8; c++) h[c] = __half_as_ushort(__float2half(acc[r][c]));
        uint4 pk;
        pk.x = h[0] | ((unsigned)h[1] << 16); pk.y = h[2] | ((unsigned)h[3] << 16);
        pk.z = h[4] | ((unsigned)h[5] << 16); pk.w = h[6] | ((unsigned)h[7] << 16);
        *(uint4*)(TrmB + rr * 256 + ((tx ^ (rr & 15)) << 4)) = pk;
    }
#pragma unroll
    for (int c = 0; c < 8; c++) {           // col-major tile
        int cc = 8 * tx + c;
        unsigned short h[8];
#pragma unroll
        for (int r = 0; r < 8; r++) h[r] = __half_as_ushort(__float2half(acc[r][c]));
        uint4 pk;
        pk.x = h[0] | ((unsigned)h[1] << 16); pk.y = h[2] | ((unsigned)h[3] << 16);
        pk.z = h[4] | ((unsigned)h[5] << 16); pk.w = h[6] | ((unsigned)h[7] << 16);
        *(uint4*)(TcmB + cc * 256 + ((ty ^ (cc & 15)) << 4)) = pk;
    }

    // ---------------- scratch pointers + init ----------------
    unsigned long long* rmsg = ws;
    unsigned long long* cmsg = ws + MSG_ONE;
    float* fb   = (float*)(ws + 2 * MSG_ONE) + (size_t)b * SCRF;
    float* ubuf = fb;                       // [0..127] u          (pair1 writes)
    float* vbuf = fb + 128;                 // [0..127] v          (pair0 writes)
    float* psum = fb + 256;                 // [0,1]=pair1 wave sums, [2,3]=pair0
    unsigned* flg = (unsigned*)(fb + 260);  // [0,1]=pair1 rendezvous, [2,3]=pair0
    unsigned long long* uNm = (unsigned long long*)(fb + 264);  // {uN, it+1}
    unsigned long long* vNm = (unsigned long long*)(fb + 266);  // {vN, it+1}

    if (t < 128) vbuf[t] = 1.0f;
    if (t == 0) {
        flg[0] = 0; flg[1] = 0; flg[2] = 0; flg[3] = 0;
        PK p0; p0.s.v = 0.0f; p0.s.tag = 0u; *uNm = p0.u;
        PK p1; p1.s.v = 1.0f; p1.s.tag = 0u; *vNm = p1.u;
    }
    __syncthreads();                        // tiles + scratch ready

    // ---------------- phase 3: 100 Sinkhorn iterations, role-split ----------------
    if (t < 128) {
        // ======== pair0: u-producer, v-consumer ========
        float vsum = 128.0f;                // sum of this block's vbuf (prev iter)
        for (int it = 0; it < ITERS; ++it) {
            const int buf = it & 1;
            const unsigned tagw = (unsigned)(it + 1);
            unsigned long long* ub = rmsg + (size_t)((buf * 16 + bi) * 16) * SLOT;

            if (t == 0) {                   // early stripe-vsum post
                PK p; p.s.v = vsum; p.s.tag = tagw;
                __hip_atomic_store(ub + (size_t)bj * SLOT + 128, p.u, __ATOMIC_RELAXED, AGENT);
            }
            // u-matvec: r_t = sum_j K[t,j] v_j (conflict-free swizzle)
            float racc = 0.f;
            {
                const char* rp = TrmB + t * 256;
                const float4* v4 = (const float4*)vbuf;
#pragma unroll
                for (int c = 0; c < 16; c++) {
                    uint4 kq = *(const uint4*)(rp + ((c ^ (t & 15)) << 4));
                    float4 va = v4[2 * c], vb = v4[2 * c + 1];
                    const __half2* h2 = (const __half2*)&kq;
                    float2 f;
                    f = __half22float2(h2[0]); racc = fmaf(f.x, va.x, fmaf(f.y, va.y, racc));
                    f = __half22float2(h2[1]); racc = fmaf(f.x, va.z, fmaf(f.y, va.w, racc));
                    f = __half22float2(h2[2]); racc = fmaf(f.x, vb.x, fmaf(f.y, vb.y, racc));
                    f = __half22float2(h2[3]); racc = fmaf(f.x, vb.z, fmaf(f.y, vb.w, racc));
                }
            }
            { PK p; p.s.v = racc; p.s.tag = tagw;
              __hip_atomic_store(ub + (size_t)bj * SLOT + t, p.u, __ATOMIC_RELAXED, AGENT); }

            // v-poll (messages produced by every block's pair1 this iteration)
            unsigned long long* cb = cmsg + (size_t)((buf * 16 + bj) * 16) * SLOT;
            bool udone = (l >= 16);
            float usv = 0.f, csum = 0.f;
            for (;;) {
                PK m[16];
#pragma unroll
                for (int s = 0; s < 16; s++)
                    m[s].u = __hip_atomic_load(cb + (size_t)s * SLOT + t,
                                               __ATOMIC_RELAXED, AGENT);
                PK um; um.u = 0ull;
                if (!udone)
                    um.u = __hip_atomic_load(cb + (size_t)l * SLOT + 128,
                                             __ATOMIC_RELAXED, AGENT);
                int cnt = 0; float a = 0.f;
#pragma unroll
                for (int s = 0; s < 16; s++) {
                    bool ok = (m[s].s.tag == tagw);
                    cnt += ok; a += ok ? m[s].s.v : 0.f;
                }
                if (!udone && um.s.tag == tagw) { usv = um.s.v; udone = true; }
                if (cnt == 16 && udone) { csum = a; break; }
                __builtin_amdgcn_s_sleep(1);
            }
            float ssum = wave_sum(l < 16 ? usv : 0.f);   // all-rows sum of u
            // this iteration's uN from pair1 mailbox (written before pair1's v-store,
            // which we just consumed -> spin exits immediately)
            PK un;
            for (;;) {
                un.u = __hip_atomic_load(uNm, __ATOMIC_RELAXED, WG);
                if (un.s.tag == tagw) break;
                __builtin_amdgcn_s_sleep(1);
            }
            const float uNv = un.s.v;
            const float vNv = 1.0f / (E * (ssum + uNv));
            float vj = 1.0f / (csum + E * uNv);
            vbuf[t] = vj;
            float wsm = wave_sum(vj);
            if (l == 0) psum[2 + w] = wsm;
            if (t == 0) { PK p; p.s.v = vNv; p.s.tag = tagw;
                          __hip_atomic_store(vNm, p.u, __ATOMIC_RELAXED, WG); }
            // pair0 rendezvous: both waves' vbuf writes visible before next u-matvec
            asm volatile("s_waitcnt vmcnt(0)" ::: "memory");
            if (l == 0) __hip_atomic_store(&flg[2 + w], tagw, __ATOMIC_RELEASE, WG);
            while (__hip_atomic_load(&flg[2 + (w ^ 1)], __ATOMIC_ACQUIRE, WG) < tagw)
                __builtin_amdgcn_s_sleep(1);
            vsum = psum[2] + psum[3];
        }
    } else {
        // ======== pair1: u-consumer, v-producer ========
        const int tr = t - 128;
        const int pw = w - 2;               // 0,1
        for (int it = 0; it < ITERS; ++it) {
            const int buf = it & 1;
            const unsigned tagw = (unsigned)(it + 1);
            unsigned long long* ub = rmsg + (size_t)((buf * 16 + bi) * 16) * SLOT;

            // u-poll: starts BEFORE producers finish -> steady-state detection
            bool vdone = (l >= 16);
            float vsv = 0.f, rsum = 0.f;
            for (;;) {
                PK m[16];
#pragma unroll
                for (int s = 0; s < 16; s++)
                    m[s].u = __hip_atomic_load(ub + (size_t)s * SLOT + tr,
                                               __ATOMIC_RELAXED, AGENT);
                PK vm; vm.u = 0ull;
                if (!vdone)
                    vm.u = __hip_atomic_load(ub + (size_t)l * SLOT + 128,
                                             __ATOMIC_RELAXED, AGENT);
                int cnt = 0; float a = 0.f;
#pragma unroll
                for (int s = 0; s < 16; s++) {
                    bool ok = (m[s].s.tag == tagw);
                    cnt += ok; a += ok ? m[s].s.v : 0.f;
                }
                if (!vdone && vm.s.tag == tagw) { vsv = vm.s.v; vdone = true; }
                if (cnt == 16 && vdone) { rsum = a; break; }
                __builtin_amdgcn_s_sleep(1);
            }
            float ssum = wave_sum(l < 16 ? vsv : 0.f);   // all-cols sum of v
            // previous iteration's vN from pair0 mailbox (written long ago)
            PK vn;
            for (;;) {
                vn.u = __hip_atomic_load(vNm, __ATOMIC_RELAXED, WG);
                if (vn.s.tag == (unsigned)it) break;
                __builtin_amdgcn_s_sleep(1);
            }
            const float vNv = vn.s.v;
            const float uNv = 1.0f / (E * (ssum + vNv));
            float ui = 1.0f / (rsum + E * vNv);
            ubuf[tr] = ui;
            float wsm = wave_sum(ui);
            if (l == 0) psum[pw] = wsm;
            if (t == 128) { PK p; p.s.v = uNv; p.s.tag = tagw;
                            __hip_atomic_store(uNm, p.u, __ATOMIC_RELAXED, WG); }
            // pair1 rendezvous: full ubuf visible before v-matvec reads it
            asm volatile("s_waitcnt vmcnt(0)" ::: "memory");
            if (l == 0) __hip_atomic_store(&flg[pw], tagw, __ATOMIC_RELEASE, WG);
            while (__hip_atomic_load(&flg[pw ^ 1], __ATOMIC_ACQUIRE, WG) < tagw)
                __builtin_amdgcn_s_sleep(1);
            float usum = psum[0] + psum[1];

            // v-phase: post stripe-usum early, then col matvec + store
            unsigned long long* cb = cmsg + (size_t)((buf * 16 + bj) * 16) * SLOT;
            if (t == 128) { PK p; p.s.v = usum; p.s.tag = tagw;
                __hip_atomic_store(cb + (size_t)bi * SLOT + 128, p.u, __ATOMIC_RELAXED, AGENT); }
            float cacc = 0.f;
            {
                const char* cp = TcmB + tr * 256;
                const float4* u4 = (const float4*)ubuf;
#pragma unroll
                for (int c = 0; c < 16; c++) {
                    uint4 kq = *(const uint4*)(cp + ((c ^ (tr & 15)) << 4));
                    float4 ua = u4[2 * c], ub2 = u4[2 * c + 1];
                    const __half2* h2 = (const __half2*)&kq;
                    float2 f;
                    f = __half22float2(h2[0]); cacc = fmaf(f.x, ua.x, fmaf(f.y, ua.y, cacc));
                    f = __half22float2(h2[1]); cacc = fmaf(f.x, ua.z, fmaf(f.y, ua.w, cacc));
                    f = __half22float2(h2[2]); cacc = fmaf(f.x, ub2.x, fmaf(f.y, ub2.y, cacc));
                    f = __half22float2(h2[3]); cacc = fmaf(f.x, ub2.z, fmaf(f.y, ub2.w, cacc));
                }
            }
            { PK p; p.s.v = cacc; p.s.tag = tagw;
              __hip_atomic_store(cb + (size_t)bi * SLOT + tr, p.u, __ATOMIC_RELAXED, AGENT); }
        }
    }
    __syncthreads();                        // loop done; ubuf/vbuf/mailboxes final

    // ---------------- phase 4: epilogue P = u_i K0 v_j ----------------
    PK uNp, vNp; uNp.u = *uNm; vNp.u = *vNm;
    const float uN = uNp.s.v, vN = vNp.s.v;

    float* P  = out;                        // [2048][2048]
    float* PA = out + (size_t)2048 * 2048;  // [2049][2049]
    float2 vv = *(const float2*)&vbuf[2 * l];
#pragma unroll 2
    for (int rr2 = 0; rr2 < 32; rr2++) {
        int i = 32 * w + rr2;
        float ui = ubuf[i];
        const char* rp = TrmB + i * 256;
        int c = l >> 2;                     // logical chunk of col 2l
        __half2 h2 = *(const __half2*)(rp + ((c ^ (i & 15)) << 4) + (l & 3) * 4);
        float2 kf = __half22float2(h2);
        float p0 = ui * kf.x * vv.x;
        float p1 = ui * kf.y * vv.y;
        size_t gi = (size_t)(gi0 + i);
        *(float2*)&P[gi * 2048 + gj0 + 2 * l] = make_float2(p0, p1);
        PA[gi * 2049 + gj0 + 2 * l]     = p0;
        PA[gi * 2049 + gj0 + 2 * l + 1] = p1;
        if (bj == 15 && l == 0) PA[gi * 2049 + 2048] = ui * E * vN;     // last col
    }
    if (bi == 15 && w == 0) {               // last row + corner
        PA[(size_t)2048 * 2049 + gj0 + 2 * l]     = uN * E * vv.x;
        PA[(size_t)2048 * 2049 + gj0 + 2 * l + 1] = uN * E * vv.y;
        if (bj == 15 && l == 0) PA[(size_t)2048 * 2049 + 2048] = uN * E * vN;
    }
}

extern "C" void kernel_launch(void* const* d_in, const int* in_sizes, int n_in,
                              void* d_out, int out_size, void* d_ws, size_t ws_size,
                              hipStream_t stream)
{
    (void)in_sizes; (void)n_in; (void)out_size; (void)ws_size;
    const float* Q  = (const float*)d_in[0];
    const float* R  = (const float*)d_in[1];
    const float* zp = (const float*)d_in[2];
    float* out = (float*)d_out;
    unsigned long long* ws = (unsigned long long*)d_ws;
    void* args[] = { (void*)&Q, (void*)&R, (void*)&zp, (void*)&out, (void*)&ws };
    // 256 blocks == 256 CUs, 64 KiB LDS, 1 block/CU -> co-resident for spin-wait.
    // No memset needed: iteration tags (1..100) self-validate against 0xAA poison.
    hipLaunchCooperativeKernel((const void*)sinkhorn_fused, dim3(256), dim3(256),
                               args, 0, stream);
}

// Round 3
// 1108.202 us; speedup vs baseline: 1.1656x; 1.1656x over previous
//
#include <hip/hip_runtime.h>
#include <hip/hip_fp16.h>

#define ITERS 100
#define AGENT __HIP_MEMORY_SCOPE_AGENT

// 8-byte message: fp32 value + iteration tag, moved as ONE relaxed agent-scope
// atomic. Tag==it+1 validates the value (poison 0xAAAAAAAA never matches).
// Poll-is-read: observing the tag IS both detection and data delivery -> the
// phase critical path is a single coherent hop (store visible -> load sees it).
//
// Round-3 deltas vs the 908us baseline (structure otherwise identical):
//  * ubuf/vbuf/psums live in LDS (65KB static; gfx950 allows 160KB/WG).
//    Matvec vector reads become wave-broadcast LDS loads; u->v handoff is
//    LDS + __syncthreads instead of global store+ack (round-2 measured a
//    global rendezvous at ~0.8us -- that cost was in the baseline too).
//  * Poll loop is 2-deep pipelined: a fresh load batch is always in flight
//    while the previous one is tag-checked (halves detection granularity).
union PK { unsigned long long u; struct { float v; unsigned tag; } s; };

// ws layout (8-byte units):
//   rmsg[2][16][16][136] : u-phase, [buf][bi][src_bj][row 0..127, 128 = src stripe vsum]
//   cmsg[2][16][16][136] : v-phase, [buf][bj][src_bi][col 0..127, 128 = src stripe usum]
#define SLOT 136
#define MSG_ONE (2 * 16 * 16 * SLOT)

__device__ __forceinline__ float wave_sum(float p) {
    p += __shfl_xor(p, 1, 64);
    p += __shfl_xor(p, 2, 64);
    p += __shfl_xor(p, 4, 64);
    p += __shfl_xor(p, 8, 64);
    p += __shfl_xor(p, 16, 64);
    p += __shfl_xor(p, 32, 64);
    return p;
}

__global__ void __launch_bounds__(256, 1)
sinkhorn_fused(const float* __restrict__ Q, const float* __restrict__ R,
               const float* __restrict__ zp, float* __restrict__ out,
               unsigned long long* __restrict__ ws)
{
    // 65 KiB LDS: 64 KiB GEMM staging / fp16 tiles (aliased) + 1.1 KiB u/v.
    __shared__ __align__(16) char smem[66688];
    float* As = (float*)smem;               // [2][32][128] k-major A slabs
    float* Bs = (float*)(smem + 32768);     // [2][32][128] k-major B slabs
    char*  TrmB = smem;                     // [128 rows][16 chunks of 16B], chunk-swizzled
    char*  TcmB = smem + 32768;             // [128 cols][16 chunks of 16B], chunk-swizzled
    float* ubuf = (float*)(smem + 65536);   // [0..127] u, [128..129] wave partial sums
    float* vbuf = (float*)(smem + 66080);   // [0..127] v, [128..129] wave partial sums

    const int t  = threadIdx.x;
    const int b  = blockIdx.x;
    const int bi = b >> 4, bj = b & 15;
    const int tx = t & 15, ty = t >> 4;
    const int l  = t & 63, w  = t >> 6;
    const int gi0 = bi * 128, gj0 = bj * 128;

    // ---------------- phase 1: 128x128 score tile, fp32 GEMM K=512 ----------------
    float acc[8][8];
#pragma unroll
    for (int r = 0; r < 8; r++)
#pragma unroll
        for (int c = 0; c < 8; c++) acc[r][c] = 0.f;

    const int lr = t & 31, lc4 = t >> 5;
    const float* Qb = Q + (size_t)gi0 * 512;
    const float* Rb = R + (size_t)gj0 * 512;

    float4 qa[4], ra[4];
#pragma unroll
    for (int i = 0; i < 4; i++) {
        qa[i] = *(const float4*)(Qb + (size_t)(lr + 32 * i) * 512 + 4 * lc4);
        ra[i] = *(const float4*)(Rb + (size_t)(lr + 32 * i) * 512 + 4 * lc4);
    }
#pragma unroll
    for (int i = 0; i < 4; i++) {
        int row = lr + 32 * i;
        As[(4*lc4+0)*128 + row] = qa[i].x;  As[(4*lc4+1)*128 + row] = qa[i].y;
        As[(4*lc4+2)*128 + row] = qa[i].z;  As[(4*lc4+3)*128 + row] = qa[i].w;
        Bs[(4*lc4+0)*128 + row] = ra[i].x;  Bs[(4*lc4+1)*128 + row] = ra[i].y;
        Bs[(4*lc4+2)*128 + row] = ra[i].z;  Bs[(4*lc4+3)*128 + row] = ra[i].w;
    }
    __syncthreads();

    for (int ks = 0; ks < 16; ks++) {
        if (ks < 15) {
            int k0 = (ks + 1) * 32;
#pragma unroll
            for (int i = 0; i < 4; i++) {
                qa[i] = *(const float4*)(Qb + (size_t)(lr+32*i)*512 + k0 + 4*lc4);
                ra[i] = *(const float4*)(Rb + (size_t)(lr+32*i)*512 + k0 + 4*lc4);
            }
        }
        const float* A = As + (ks & 1) * (32 * 128);
        const float* B = Bs + (ks & 1) * (32 * 128);
#pragma unroll 4
        for (int k = 0; k < 32; k++) {
            float4 a0 = *(const float4*)(A + k*128 + 8*ty);
            float4 a1 = *(const float4*)(A + k*128 + 8*ty + 4);
            float4 b0 = *(const float4*)(B + k*128 + 8*tx);
            float4 b1 = *(const float4*)(B + k*128 + 8*tx + 4);
            float av[8] = {a0.x,a0.y,a0.z,a0.w,a1.x,a1.y,a1.z,a1.w};
            float bv[8] = {b0.x,b0.y,b0.z,b0.w,b1.x,b1.y,b1.z,b1.w};
#pragma unroll
            for (int r = 0; r < 8; r++)
#pragma unroll
                for (int c = 0; c < 8; c++)
                    acc[r][c] = fmaf(av[r], bv[c], acc[r][c]);
        }
        if (ks < 15) {
            __syncthreads();
            float* An = As + ((ks+1) & 1) * (32 * 128);
            float* Bn = Bs + ((ks+1) & 1) * (32 * 128);
#pragma unroll
            for (int i = 0; i < 4; i++) {
                int row = lr + 32 * i;
                An[(4*lc4+0)*128 + row] = qa[i].x;  An[(4*lc4+1)*128 + row] = qa[i].y;
                An[(4*lc4+2)*128 + row] = qa[i].z;  An[(4*lc4+3)*128 + row] = qa[i].w;
                Bn[(4*lc4+0)*128 + row] = ra[i].x;  Bn[(4*lc4+1)*128 + row] = ra[i].y;
                Bn[(4*lc4+2)*128 + row] = ra[i].z;  Bn[(4*lc4+3)*128 + row] = ra[i].w;
            }
            __syncthreads();
        }
    }
    __syncthreads();                        // As/Bs dead; LDS becomes Trm/Tcm

    // ---------------- phase 2: K0 = exp(score*10) -> swizzled fp16 tiles ----------------
    // Element (i,j): logical chunk c=j/8 stored at physical chunk c^(i&15).
    const float E = expf(zp[0] * 10.0f);
#pragma unroll
    for (int r = 0; r < 8; r++)
#pragma unroll
        for (int c = 0; c < 8; c++) acc[r][c] = expf(acc[r][c] * 10.0f);

#pragma unroll
    for (int r = 0; r < 8; r++) {           // row-major tile: one 16B chunk per row
        int rr = 8 * ty + r;
        unsigned short h[8];
#pragma unroll
        for (int c = 0; c < 8; c++) h[c] = __half_as_ushort(__float2half(acc[r][c]));
        uint4 pk;
        pk.x = h[0] | ((unsigned)h[1] << 16); pk.y = h[2] | ((unsigned)h[3] << 16);
        pk.z = h[4] | ((unsigned)h[5] << 16); pk.w = h[6] | ((unsigned)h[7] << 16);
        *(uint4*)(TrmB + rr * 256 + ((tx ^ (rr & 15)) << 4)) = pk;
    }
#pragma unroll
    for (int c = 0; c < 8; c++) {           // col-major tile
        int cc = 8 * tx + c;
        unsigned short h[8];
#pragma unroll
        for (int r = 0; r < 8; r++) h[r] = __half_as_ushort(__float2half(acc[r][c]));
        uint4 pk;
        pk.x = h[0] | ((unsigned)h[1] << 16); pk.y = h[2] | ((unsigned)h[3] << 16);
        pk.z = h[4] | ((unsigned)h[5] << 16); pk.w = h[6] | ((unsigned)h[7] << 16);
        *(uint4*)(TcmB + cc * 256 + ((ty ^ (cc & 15)) << 4)) = pk;
    }

    // ---------------- scratch pointers + init ----------------
    unsigned long long* rmsg = ws;
    unsigned long long* cmsg = ws + MSG_ONE;

    if (t < 128)      vbuf[t] = 1.0f;
    else if (t < 130) vbuf[t] = 64.0f;      // vbuf[128]+vbuf[129] = 128 = initial vsum
    float uN = 0.f, vN = 1.0f, vsum = 128.0f, usum = 0.f;
    __syncthreads();                        // tiles + vbuf ready

    // ---------------- phase 3: 100 Sinkhorn iterations ----------------
    for (int it = 0; it < ITERS; it++) {
        const int buf = it & 1;
        const unsigned tagw = (unsigned)(it + 1);

        // ======== u-phase: r_i = sum_j K[i,j] v_j ========
        {
            unsigned long long* base = rmsg + (size_t)((buf * 16 + bi) * 16) * SLOT;
            if (t == 128) {                 // early scalar post (no matvec dependency)
                PK p; p.s.v = vsum; p.s.tag = tagw;
                __hip_atomic_store(base + (size_t)bj * SLOT + 128, p.u, __ATOMIC_RELAXED, AGENT);
            }
            if (t < 128) {                  // full-row matvec (conflict-free swizzle)
                const char* rp = TrmB + t * 256;
                const float4* v4 = (const float4*)vbuf;   // LDS broadcast reads
                float racc = 0.f;
#pragma unroll
                for (int c = 0; c < 16; c++) {
                    uint4 kq = *(const uint4*)(rp + ((c ^ (t & 15)) << 4));
                    float4 va = v4[2 * c], vb = v4[2 * c + 1];
                    const __half2* h2 = (const __half2*)&kq;
                    float2 f;
                    f = __half22float2(h2[0]); racc = fmaf(f.x, va.x, fmaf(f.y, va.y, racc));
                    f = __half22float2(h2[1]); racc = fmaf(f.x, va.z, fmaf(f.y, va.w, racc));
                    f = __half22float2(h2[2]); racc = fmaf(f.x, vb.x, fmaf(f.y, vb.y, racc));
                    f = __half22float2(h2[3]); racc = fmaf(f.x, vb.z, fmaf(f.y, vb.w, racc));
                }
                PK p; p.s.v = racc; p.s.tag = tagw;
                __hip_atomic_store(base + (size_t)bj * SLOT + t, p.u, __ATOMIC_RELAXED, AGENT);
            }
            // poll-is-read, 2-deep pipelined: batch B issues while batch A checks.
            if (t < 128) {
                bool vdone = (l >= 16);
                float vsv = 0.f, rsum = 0.f;
                PK a[16], bm[16]; PK av, bv; av.u = 0ull; bv.u = 0ull;
                auto issue = [&](PK* arr, PK& side) {
#pragma unroll
                    for (int s = 0; s < 16; s++)
                        arr[s].u = __hip_atomic_load(base + (size_t)s * SLOT + t,
                                                     __ATOMIC_RELAXED, AGENT);
                    if (!vdone)
                        side.u = __hip_atomic_load(base + (size_t)l * SLOT + 128,
                                                   __ATOMIC_RELAXED, AGENT);
                };
                auto check = [&](PK* arr, PK& side) -> bool {
                    int cnt = 0; float a_ = 0.f;
#pragma unroll
                    for (int s = 0; s < 16; s++) {
                        bool ok = (arr[s].s.tag == tagw);
                        cnt += ok; a_ += ok ? arr[s].s.v : 0.f;
                    }
                    if (!vdone && side.s.tag == tagw) { vsv = side.s.v; vdone = true; }
                    if (cnt == 16 && vdone) { rsum = a_; return true; }
                    return false;
                };
                issue(a, av);
                for (;;) {
                    issue(bm, bv);
                    if (check(a, av)) break;
                    issue(a, av);
                    if (check(bm, bv)) break;
                }
                float ssum = wave_sum(l < 16 ? vsv : 0.f);   // all-cols sum of v
                uN = 1.0f / (E * (ssum + vN));
                float ui = 1.0f / (rsum + E * vN);
                ubuf[t] = ui;
                float wsm = wave_sum(ui);
                if (l == 0) ubuf[128 + w] = wsm;
            }
            __syncthreads();                // ubuf complete (waves 2,3 parked here)
            usum = ubuf[128] + ubuf[129];
        }

        // ======== v-phase: c_j = sum_i K[i,j] u_i ========
        {
            unsigned long long* base = cmsg + (size_t)((buf * 16 + bj) * 16) * SLOT;
            if (t == 128) {
                PK p; p.s.v = usum; p.s.tag = tagw;
                __hip_atomic_store(base + (size_t)bi * SLOT + 128, p.u, __ATOMIC_RELAXED, AGENT);
            }
            if (t < 128) {
                const char* cp = TcmB + t * 256;
                const float4* u4 = (const float4*)ubuf;   // LDS broadcast reads
                float cacc = 0.f;
#pragma unroll
                for (int c = 0; c < 16; c++) {
                    uint4 kq = *(const uint4*)(cp + ((c ^ (t & 15)) << 4));
                    float4 ua = u4[2 * c], ub = u4[2 * c + 1];
                    const __half2* h2 = (const __half2*)&kq;
                    float2 f;
                    f = __half22float2(h2[0]); cacc = fmaf(f.x, ua.x, fmaf(f.y, ua.y, cacc));
                    f = __half22float2(h2[1]); cacc = fmaf(f.x, ua.z, fmaf(f.y, ua.w, cacc));
                    f = __half22float2(h2[2]); cacc = fmaf(f.x, ub.x, fmaf(f.y, ub.y, cacc));
                    f = __half22float2(h2[3]); cacc = fmaf(f.x, ub.z, fmaf(f.y, ub.w, cacc));
                }
                PK p; p.s.v = cacc; p.s.tag = tagw;
                __hip_atomic_store(base + (size_t)bi * SLOT + t, p.u, __ATOMIC_RELAXED, AGENT);
            }
            // poll: waves 0,1 pipelined full-gather; waves 2,3 lanes<16 gather usums
            if (t < 128) {
                bool udone = (l >= 16);
                float usv = 0.f, csum = 0.f;
                PK a[16], bm[16]; PK av, bv; av.u = 0ull; bv.u = 0ull;
                auto issue = [&](PK* arr, PK& side) {
#pragma unroll
                    for (int s = 0; s < 16; s++)
                        arr[s].u = __hip_atomic_load(base + (size_t)s * SLOT + t,
                                                     __ATOMIC_RELAXED, AGENT);
                    if (!udone)
                        side.u = __hip_atomic_load(base + (size_t)l * SLOT + 128,
                                                   __ATOMIC_RELAXED, AGENT);
                };
                auto check = [&](PK* arr, PK& side) -> bool {
                    int cnt = 0; float a_ = 0.f;
#pragma unroll
                    for (int s = 0; s < 16; s++) {
                        bool ok = (arr[s].s.tag == tagw);
                        cnt += ok; a_ += ok ? arr[s].s.v : 0.f;
                    }
                    if (!udone && side.s.tag == tagw) { usv = side.s.v; udone = true; }
                    if (cnt == 16 && udone) { csum = a_; return true; }
                    return false;
                };
                issue(a, av);
                for (;;) {
                    issue(bm, bv);
                    if (check(a, av)) break;
                    issue(a, av);
                    if (check(bm, bv)) break;
                }
                float ssum = wave_sum(l < 16 ? usv : 0.f);   // all-rows sum of u
                vN = 1.0f / (E * (ssum + uN));
                float vj = 1.0f / (csum + E * uN);
                vbuf[t] = vj;
                float wsm = wave_sum(vj);
                if (l == 0) vbuf[128 + w] = wsm;
            } else {
                bool udone = (l >= 16);
                float usv = 0.f;
                while (!udone) {
                    PK um;
                    um.u = __hip_atomic_load(base + (size_t)l * SLOT + 128,
                                             __ATOMIC_RELAXED, AGENT);
                    if (um.s.tag == tagw) { usv = um.s.v; udone = true; }
                    else __builtin_amdgcn_s_sleep(1);
                }
                float ssum = wave_sum(l < 16 ? usv : 0.f);
                vN = 1.0f / (E * (ssum + uN));  // waves 2,3 need vN for epilogue
            }
            __syncthreads();                // vbuf complete
            vsum = vbuf[128] + vbuf[129];
        }
    }

    // ---------------- phase 4: epilogue P = u_i K0 v_j ----------------
    float* P  = out;                        // [2048][2048]
    float* PA = out + (size_t)2048 * 2048;  // [2049][2049]
    float2 vv = *(const float2*)&vbuf[2 * l];
#pragma unroll 2
    for (int rr2 = 0; rr2 < 32; rr2++) {
        int i = 32 * w + rr2;
        float ui = ubuf[i];
        const char* rp = TrmB + i * 256;
        int c = l >> 2;                     // logical chunk of col 2l
        __half2 h2 = *(const __half2*)(rp + ((c ^ (i & 15)) << 4) + (l & 3) * 4);
        float2 kf = __half22float2(h2);
        float p0 = ui * kf.x * vv.x;
        float p1 = ui * kf.y * vv.y;
        size_t gi = (size_t)(gi0 + i);
        *(float2*)&P[gi * 2048 + gj0 + 2 * l] = make_float2(p0, p1);
        PA[gi * 2049 + gj0 + 2 * l]     = p0;
        PA[gi * 2049 + gj0 + 2 * l + 1] = p1;
        if (bj == 15 && l == 0) PA[gi * 2049 + 2048] = ui * E * vN;     // last col
    }
    if (bi == 15 && w == 0) {               // last row + corner
        PA[(size_t)2048 * 2049 + gj0 + 2 * l]     = uN * E * vv.x;
        PA[(size_t)2048 * 2049 + gj0 + 2 * l + 1] = uN * E * vv.y;
        if (bj == 15 && l == 0) PA[(size_t)2048 * 2049 + 2048] = uN * E * vN;
    }
}

extern "C" void kernel_launch(void* const* d_in, const int* in_sizes, int n_in,
                              void* d_out, int out_size, void* d_ws, size_t ws_size,
                              hipStream_t stream)
{
    (void)in_sizes; (void)n_in; (void)out_size; (void)ws_size;
    const float* Q  = (const float*)d_in[0];
    const float* R  = (const float*)d_in[1];
    const float* zp = (const float*)d_in[2];
    float* out = (float*)d_out;
    unsigned long long* ws = (unsigned long long*)d_ws;
    void* args[] = { (void*)&Q, (void*)&R, (void*)&zp, (void*)&out, (void*)&ws };
    // 256 blocks == 256 CUs, 65 KiB LDS, 1 block/CU -> co-resident for spin-wait.
    // No memset needed: iteration tags (1..100) self-validate against 0xAA poison.
    hipLaunchCooperativeKernel((const void*)sinkhorn_fused, dim3(256), dim3(256),
                               args, 0, stream);
}

// Round 5
// 845.046 us; speedup vs baseline: 1.5286x; 1.3114x over previous
//
#include <hip/hip_runtime.h>
#include <hip/hip_fp16.h>

#define ITERS 100
#define AGENT __HIP_MEMORY_SCOPE_AGENT

// 8-byte message: fp32 value + iteration tag, moved as ONE relaxed agent-scope
// atomic. Tag==it+1 validates the value (poison 0xAAAAAAAA never matches).
// Poll-is-read: observing the tag IS both detection and data delivery -> the
// phase critical path is a single coherent hop (store visible -> load sees it).
//
// Round-5 delta vs the 908us baseline (protocol/stores byte-identical):
//   SPLIT-GATHER POLLING. All 4 waves poll: thread t covers sources
//   8*(t>>7)..8*(t>>7)+7 of row t&127 (8 slots each instead of 16), partials
//   combined through 1KiB of LDS + the existing barrier. Poll rounds are half
//   as long (finer detection quantum) and waves 2-3 begin polling while waves
//   0-1 are still in the matvec (overlap without round-2's global rendezvous).
union PK { unsigned long long u; struct { float v; unsigned tag; } s; };

// ws layout (8-byte units):
//   rmsg[2][16][16][136] : u-phase, [buf][bi][src_bj][row 0..127, 128 = src stripe vsum]
//   cmsg[2][16][16][136] : v-phase, [buf][bj][src_bi][col 0..127, 128 = src stripe usum]
//   then per-block fp32 u/v scratch (block-private, L1/L2-resident plain ld/st)
#define SLOT 136
#define MSG_ONE (2 * 16 * 16 * SLOT)
#define UV_STRIDE 272

__device__ __forceinline__ float wave_sum(float p) {
    p += __shfl_xor(p, 1, 64);
    p += __shfl_xor(p, 2, 64);
    p += __shfl_xor(p, 4, 64);
    p += __shfl_xor(p, 8, 64);
    p += __shfl_xor(p, 16, 64);
    p += __shfl_xor(p, 32, 64);
    return p;
}

__global__ void __launch_bounds__(256, 1)
sinkhorn_fused(const float* __restrict__ Q, const float* __restrict__ R,
               const float* __restrict__ zp, float* __restrict__ out,
               unsigned long long* __restrict__ ws)
{
    // 65 KiB LDS: 64 KiB GEMM staging / fp16 tiles (aliased) + 1 KiB poll partials.
    __shared__ __align__(16) char smem[66560];
    float* As = (float*)smem;               // [2][32][128] k-major A slabs
    float* Bs = (float*)(smem + 32768);     // [2][32][128] k-major B slabs
    char*  TrmB = smem;                     // [128 rows][16 chunks of 16B], chunk-swizzled
    char*  TcmB = smem + 32768;             // [128 cols][16 chunks of 16B], chunk-swizzled
    float* part = (float*)(smem + 65536);   // [256] split-poll partial sums

    const int t  = threadIdx.x;
    const int b  = blockIdx.x;
    const int bi = b >> 4, bj = b & 15;
    const int tx = t & 15, ty = t >> 4;
    const int l  = t & 63, w  = t >> 6;
    const int gi0 = bi * 128, gj0 = bj * 128;

    // ---------------- phase 1: 128x128 score tile, fp32 GEMM K=512 ----------------
    float acc[8][8];
#pragma unroll
    for (int r = 0; r < 8; r++)
#pragma unroll
        for (int c = 0; c < 8; c++) acc[r][c] = 0.f;

    const int lr = t & 31, lc4 = t >> 5;
    const float* Qb = Q + (size_t)gi0 * 512;
    const float* Rb = R + (size_t)gj0 * 512;

    float4 qa[4], ra[4];
#pragma unroll
    for (int i = 0; i < 4; i++) {
        qa[i] = *(const float4*)(Qb + (size_t)(lr + 32 * i) * 512 + 4 * lc4);
        ra[i] = *(const float4*)(Rb + (size_t)(lr + 32 * i) * 512 + 4 * lc4);
    }
#pragma unroll
    for (int i = 0; i < 4; i++) {
        int row = lr + 32 * i;
        As[(4*lc4+0)*128 + row] = qa[i].x;  As[(4*lc4+1)*128 + row] = qa[i].y;
        As[(4*lc4+2)*128 + row] = qa[i].z;  As[(4*lc4+3)*128 + row] = qa[i].w;
        Bs[(4*lc4+0)*128 + row] = ra[i].x;  Bs[(4*lc4+1)*128 + row] = ra[i].y;
        Bs[(4*lc4+2)*128 + row] = ra[i].z;  Bs[(4*lc4+3)*128 + row] = ra[i].w;
    }
    __syncthreads();

    for (int ks = 0; ks < 16; ks++) {
        if (ks < 15) {
            int k0 = (ks + 1) * 32;
#pragma unroll
            for (int i = 0; i < 4; i++) {
                qa[i] = *(const float4*)(Qb + (size_t)(lr+32*i)*512 + k0 + 4*lc4);
                ra[i] = *(const float4*)(Rb + (size_t)(lr+32*i)*512 + k0 + 4*lc4);
            }
        }
        const float* A = As + (ks & 1) * (32 * 128);
        const float* B = Bs + (ks & 1) * (32 * 128);
#pragma unroll 4
        for (int k = 0; k < 32; k++) {
            float4 a0 = *(const float4*)(A + k*128 + 8*ty);
            float4 a1 = *(const float4*)(A + k*128 + 8*ty + 4);
            float4 b0 = *(const float4*)(B + k*128 + 8*tx);
            float4 b1 = *(const float4*)(B + k*128 + 8*tx + 4);
            float av[8] = {a0.x,a0.y,a0.z,a0.w,a1.x,a1.y,a1.z,a1.w};
            float bv[8] = {b0.x,b0.y,b0.z,b0.w,b1.x,b1.y,b1.z,b1.w};
#pragma unroll
            for (int r = 0; r < 8; r++)
#pragma unroll
                for (int c = 0; c < 8; c++)
                    acc[r][c] = fmaf(av[r], bv[c], acc[r][c]);
        }
        if (ks < 15) {
            __syncthreads();
            float* An = As + ((ks+1) & 1) * (32 * 128);
            float* Bn = Bs + ((ks+1) & 1) * (32 * 128);
#pragma unroll
            for (int i = 0; i < 4; i++) {
                int row = lr + 32 * i;
                An[(4*lc4+0)*128 + row] = qa[i].x;  An[(4*lc4+1)*128 + row] = qa[i].y;
                An[(4*lc4+2)*128 + row] = qa[i].z;  An[(4*lc4+3)*128 + row] = qa[i].w;
                Bn[(4*lc4+0)*128 + row] = ra[i].x;  Bn[(4*lc4+1)*128 + row] = ra[i].y;
                Bn[(4*lc4+2)*128 + row] = ra[i].z;  Bn[(4*lc4+3)*128 + row] = ra[i].w;
            }
            __syncthreads();
        }
    }
    __syncthreads();                        // As/Bs dead; LDS becomes Trm/Tcm

    // ---------------- phase 2: K0 = exp(score*10) -> swizzled fp16 tiles ----------------
    // Element (i,j): logical chunk c=j/8 stored at physical chunk c^(i&15).
    const float E = expf(zp[0] * 10.0f);
#pragma unroll
    for (int r = 0; r < 8; r++)
#pragma unroll
        for (int c = 0; c < 8; c++) acc[r][c] = expf(acc[r][c] * 10.0f);

#pragma unroll
    for (int r = 0; r < 8; r++) {           // row-major tile: one 16B chunk per row
        int rr = 8 * ty + r;
        unsigned short h[8];
#pragma unroll
        for (int c = 0; c < 8; c++) h[c] = __half_as_ushort(__float2half(acc[r][c]));
        uint4 pk;
        pk.x = h[0] | ((unsigned)h[1] << 16); pk.y = h[2] | ((unsigned)h[3] << 16);
        pk.z = h[4] | ((unsigned)h[5] << 16); pk.w = h[6] | ((unsigned)h[7] << 16);
        *(uint4*)(TrmB + rr * 256 + ((tx ^ (rr & 15)) << 4)) = pk;
    }
#pragma unroll
    for (int c = 0; c < 8; c++) {           // col-major tile
        int cc = 8 * tx + c;
        unsigned short h[8];
#pragma unroll
        for (int r = 0; r < 8; r++) h[r] = __half_as_ushort(__float2half(acc[r][c]));
        uint4 pk;
        pk.x = h[0] | ((unsigned)h[1] << 16); pk.y = h[2] | ((unsigned)h[3] << 16);
        pk.z = h[4] | ((unsigned)h[5] << 16); pk.w = h[6] | ((unsigned)h[7] << 16);
        *(uint4*)(TcmB + cc * 256 + ((ty ^ (cc & 15)) << 4)) = pk;
    }

    // ---------------- scratch pointers + init ----------------
    unsigned long long* rmsg = ws;
    unsigned long long* cmsg = ws + MSG_ONE;
    float* uvb  = (float*)(ws + 2 * MSG_ONE) + b * UV_STRIDE;
    float* ubuf = uvb;                      // [0..127] u, [128..129] wave partial sums
    float* vbuf = uvb + 136;                // [0..127] v, [128..129] wave partial sums

    if (t < 128)      vbuf[t] = 1.0f;
    else if (t < 130) vbuf[t] = 64.0f;      // vbuf[128]+vbuf[129] = 128 = initial vsum
    float uN = 0.f, vN = 1.0f, vsum = 128.0f, usum = 0.f;
    __syncthreads();                        // tiles + vbuf ready

    // ---------------- phase 3: 100 Sinkhorn iterations ----------------
    for (int it = 0; it < ITERS; it++) {
        const int buf = it & 1;
        const unsigned tagw = (unsigned)(it + 1);

        // ======== u-phase: r_i = sum_j K[i,j] v_j ========
        {
            unsigned long long* base = rmsg + (size_t)((buf * 16 + bi) * 16) * SLOT;
            if (t == 128) {                 // early scalar post (no matvec dependency)
                PK p; p.s.v = vsum; p.s.tag = tagw;
                __hip_atomic_store(base + (size_t)bj * SLOT + 128, p.u, __ATOMIC_RELAXED, AGENT);
            }
            if (t < 128) {                  // full-row matvec (conflict-free swizzle)
                const char* rp = TrmB + t * 256;
                const float4* v4 = (const float4*)vbuf;
                float racc = 0.f;
#pragma unroll
                for (int c = 0; c < 16; c++) {
                    uint4 kq = *(const uint4*)(rp + ((c ^ (t & 15)) << 4));
                    float4 va = v4[2 * c], vb = v4[2 * c + 1];
                    const __half2* h2 = (const __half2*)&kq;
                    float2 f;
                    f = __half22float2(h2[0]); racc = fmaf(f.x, va.x, fmaf(f.y, va.y, racc));
                    f = __half22float2(h2[1]); racc = fmaf(f.x, va.z, fmaf(f.y, va.w, racc));
                    f = __half22float2(h2[2]); racc = fmaf(f.x, vb.x, fmaf(f.y, vb.y, racc));
                    f = __half22float2(h2[3]); racc = fmaf(f.x, vb.z, fmaf(f.y, vb.w, racc));
                }
                PK p; p.s.v = racc; p.s.tag = tagw;
                __hip_atomic_store(base + (size_t)bj * SLOT + t, p.u, __ATOMIC_RELAXED, AGENT);
            }
            // split poll: thread t covers sources 8*(t>>7)..+7 of row t&127.
            // Waves 2,3 start polling while waves 0,1 are still in the matvec.
            float ssum_v = 0.f;             // waves 0,1: sum of 16 stripe vsums
            {
                const int row  = t & 127;
                const int half = t >> 7;
                bool sdone = (half == 1) || (l >= 16);   // sides: waves 0,1 lanes<16
                float vsv = 0.f, pacc = 0.f;
                unsigned long long* rb = base + (size_t)(8 * half) * SLOT + row;
                for (;;) {
                    PK m[8];
#pragma unroll
                    for (int s = 0; s < 8; s++)
                        m[s].u = __hip_atomic_load(rb + (size_t)s * SLOT,
                                                   __ATOMIC_RELAXED, AGENT);
                    PK vm; vm.u = 0ull;
                    if (!sdone)
                        vm.u = __hip_atomic_load(base + (size_t)l * SLOT + 128,
                                                 __ATOMIC_RELAXED, AGENT);
                    int cnt = 0; float a = 0.f;
#pragma unroll
                    for (int s = 0; s < 8; s++) {
                        bool ok = (m[s].s.tag == tagw);
                        cnt += ok; a += ok ? m[s].s.v : 0.f;
                    }
                    if (!sdone && vm.s.tag == tagw) { vsv = vm.s.v; sdone = true; }
                    if (cnt == 8 && sdone) { pacc = a; break; }
                    __builtin_amdgcn_s_sleep(1);
                }
                part[t] = pacc;
                ssum_v = wave_sum(l < 16 ? vsv : 0.f);   // all-cols sum of v
            }
            __syncthreads();                // both halves' partials in LDS
            if (t < 128) {
                float rsum = part[t] + part[t + 128];
                uN = 1.0f / (E * (ssum_v + vN));
                float ui = 1.0f / (rsum + E * vN);
                ubuf[t] = ui;
                float wsm = wave_sum(ui);
                if (l == 0) ubuf[128 + w] = wsm;
            }
            __syncthreads();                // ubuf complete
            usum = ubuf[128] + ubuf[129];
        }

        // ======== v-phase: c_j = sum_i K[i,j] u_i ========
        {
            unsigned long long* base = cmsg + (size_t)((buf * 16 + bj) * 16) * SLOT;
            if (t == 128) {
                PK p; p.s.v = usum; p.s.tag = tagw;
                __hip_atomic_store(base + (size_t)bi * SLOT + 128, p.u, __ATOMIC_RELAXED, AGENT);
            }
            if (t < 128) {
                const char* cp = TcmB + t * 256;
                const float4* u4 = (const float4*)ubuf;
                float cacc = 0.f;
#pragma unroll
                for (int c = 0; c < 16; c++) {
                    uint4 kq = *(const uint4*)(cp + ((c ^ (t & 15)) << 4));
                    float4 ua = u4[2 * c], ub = u4[2 * c + 1];
                    const __half2* h2 = (const __half2*)&kq;
                    float2 f;
                    f = __half22float2(h2[0]); cacc = fmaf(f.x, ua.x, fmaf(f.y, ua.y, cacc));
                    f = __half22float2(h2[1]); cacc = fmaf(f.x, ua.z, fmaf(f.y, ua.w, cacc));
                    f = __half22float2(h2[2]); cacc = fmaf(f.x, ub.x, fmaf(f.y, ub.y, cacc));
                    f = __half22float2(h2[3]); cacc = fmaf(f.x, ub.z, fmaf(f.y, ub.w, cacc));
                }
                PK p; p.s.v = cacc; p.s.tag = tagw;
                __hip_atomic_store(base + (size_t)bi * SLOT + t, p.u, __ATOMIC_RELAXED, AGENT);
            }
            // split poll; sides polled by lanes<16 of ALL waves (every wave needs vN)
            float ssum_u = 0.f;
            {
                const int row  = t & 127;
                const int half = t >> 7;
                bool sdone = (l >= 16);
                float usv = 0.f, pacc = 0.f;
                unsigned long long* rb = base + (size_t)(8 * half) * SLOT + row;
                for (;;) {
                    PK m[8];
#pragma unroll
                    for (int s = 0; s < 8; s++)
                        m[s].u = __hip_atomic_load(rb + (size_t)s * SLOT,
                                                   __ATOMIC_RELAXED, AGENT);
                    PK um; um.u = 0ull;
                    if (!sdone)
                        um.u = __hip_atomic_load(base + (size_t)l * SLOT + 128,
                                                 __ATOMIC_RELAXED, AGENT);
                    int cnt = 0; float a = 0.f;
#pragma unroll
                    for (int s = 0; s < 8; s++) {
                        bool ok = (m[s].s.tag == tagw);
                        cnt += ok; a += ok ? m[s].s.v : 0.f;
                    }
                    if (!sdone && um.s.tag == tagw) { usv = um.s.v; sdone = true; }
                    if (cnt == 8 && sdone) { pacc = a; break; }
                    __builtin_amdgcn_s_sleep(1);
                }
                part[t] = pacc;
                ssum_u = wave_sum(l < 16 ? usv : 0.f);   // all-rows sum of u
            }
            vN = 1.0f / (E * (ssum_u + uN));             // all waves (epilogue needs vN)
            __syncthreads();                // both halves' partials in LDS
            if (t < 128) {
                float csum = part[t] + part[t + 128];
                float vj = 1.0f / (csum + E * uN);
                vbuf[t] = vj;
                float wsm = wave_sum(vj);
                if (l == 0) vbuf[128 + w] = wsm;
            }
            __syncthreads();                // vbuf complete
            vsum = vbuf[128] + vbuf[129];
        }
    }

    // ---------------- phase 4: epilogue P = u_i K0 v_j ----------------
    float* P  = out;                        // [2048][2048]
    float* PA = out + (size_t)2048 * 2048;  // [2049][2049]
    float2 vv = *(const float2*)&vbuf[2 * l];
#pragma unroll 2
    for (int rr2 = 0; rr2 < 32; rr2++) {
        int i = 32 * w + rr2;
        float ui = ubuf[i];
        const char* rp = TrmB + i * 256;
        int c = l >> 2;                     // logical chunk of col 2l
        __half2 h2 = *(const __half2*)(rp + ((c ^ (i & 15)) << 4) + (l & 3) * 4);
        float2 kf = __half22float2(h2);
        float p0 = ui * kf.x * vv.x;
        float p1 = ui * kf.y * vv.y;
        size_t gi = (size_t)(gi0 + i);
        *(float2*)&P[gi * 2048 + gj0 + 2 * l] = make_float2(p0, p1);
        PA[gi * 2049 + gj0 + 2 * l]     = p0;
        PA[gi * 2049 + gj0 + 2 * l + 1] = p1;
        if (bj == 15 && l == 0) PA[gi * 2049 + 2048] = ui * E * vN;     // last col
    }
    if (bi == 15 && w == 0) {               // last row + corner
        PA[(size_t)2048 * 2049 + gj0 + 2 * l]     = uN * E * vv.x;
        PA[(size_t)2048 * 2049 + gj0 + 2 * l + 1] = uN * E * vv.y;
        if (bj == 15 && l == 0) PA[(size_t)2048 * 2049 + 2048] = uN * E * vN;
    }
}

extern "C" void kernel_launch(void* const* d_in, const int* in_sizes, int n_in,
                              void* d_out, int out_size, void* d_ws, size_t ws_size,
                              hipStream_t stream)
{
    (void)in_sizes; (void)n_in; (void)out_size; (void)ws_size;
    const float* Q  = (const float*)d_in[0];
    const float* R  = (const float*)d_in[1];
    const float* zp = (const float*)d_in[2];
    float* out = (float*)d_out;
    unsigned long long* ws = (unsigned long long*)d_ws;
    void* args[] = { (void*)&Q, (void*)&R, (void*)&zp, (void*)&out, (void*)&ws };
    // 256 blocks == 256 CUs, 65 KiB LDS, 1 block/CU -> co-resident for spin-wait.
    // No memset needed: iteration tags (1..100) self-validate against 0xAA poison.
    hipLaunchCooperativeKernel((const void*)sinkhorn_fused, dim3(256), dim3(256),
                               args, 0, stream);
}